// Round 1
// baseline (1498.623 us; speedup 1.0000x reference)
//
#include <hip/hip_runtime.h>
#include <hip/hip_bf16.h>

#define NPT   16384
#define NQ    512
#define NS    32
#define BATCH 8

// ---------------------------------------------------------------------------
// Kernel 1: furthest point sampling. One block per batch, 1024 threads,
// 16 points per thread held in registers. Exact fp32 (no FMA contraction)
// to match the numpy/jax reference; first-occurrence argmax via packed key.
// ---------------------------------------------------------------------------
__global__ __launch_bounds__(1024) void fps_kernel(const float* __restrict__ xyz,
                                                   float* __restrict__ new_xyz)
{
    const int b = blockIdx.x;
    const int t = threadIdx.x;
    const float* xb = xyz + (size_t)b * NPT * 3;

    float xr[16], yr[16], zr[16], dr[16];
    const float INF = __int_as_float(0x7f800000);
#pragma unroll
    for (int i = 0; i < 16; ++i) {
        const int p = i * 1024 + t;
        xr[i] = xb[p * 3 + 0];
        yr[i] = xb[p * 3 + 1];
        zr[i] = xb[p * 3 + 2];
        dr[i] = INF;
    }

    __shared__ unsigned long long red[2][16];

    float px = xb[0], py = xb[1], pz = xb[2];

    for (int s = 0; s < NQ; ++s) {
        if (t == 0) {
            float* o = new_xyz + ((size_t)b * NQ + s) * 3;
            o[0] = px; o[1] = py; o[2] = pz;
        }
        if (s == NQ - 1) break;

        // update min-dists and track local argmax (smallest index on ties)
        float dmax = -1.0f;
        int   bi_  = 0;
#pragma unroll
        for (int i = 15; i >= 0; --i) {
            const float dx = __fsub_rn(xr[i], px);
            const float dy = __fsub_rn(yr[i], py);
            const float dz = __fsub_rn(zr[i], pz);
            const float d  = __fadd_rn(__fadd_rn(__fmul_rn(dx, dx), __fmul_rn(dy, dy)),
                                       __fmul_rn(dz, dz));
            const float dn = fminf(dr[i], d);
            dr[i] = dn;
            if (dn >= dmax) { dmax = dn; bi_ = i; }   // descending i => first occurrence wins
        }

        const unsigned pidx = (unsigned)(bi_ * 1024 + t);
        unsigned long long best =
            ((unsigned long long)__float_as_uint(dmax) << 32) | (unsigned)(~pidx);

        // wave butterfly max (ties -> larger ~idx -> smaller idx)
#pragma unroll
        for (int m = 32; m >= 1; m >>= 1) {
            const unsigned long long o = __shfl_xor(best, m, 64);
            if (o > best) best = o;
        }
        if ((t & 63) == 0) red[s & 1][t >> 6] = best;
        __syncthreads();
        best = red[s & 1][0];
#pragma unroll
        for (int w = 1; w < 16; ++w) {
            const unsigned long long o = red[s & 1][w];
            if (o > best) best = o;
        }
        const int nxt = (int)(~(unsigned)best);
        px = xb[nxt * 3 + 0];
        py = xb[nxt * 3 + 1];
        pz = xb[nxt * 3 + 2];
    }
}

// ---------------------------------------------------------------------------
// Kernel 2: ball query. One wave per (b,s) query; ascending index scan with
// ballot + prefix popcount collects exactly the 32 smallest in-radius indices.
// ---------------------------------------------------------------------------
__global__ __launch_bounds__(256) void bq_kernel(const float* __restrict__ xyz,
                                                 const float* __restrict__ newxyz,
                                                 int* __restrict__ gidx)
{
    const int wid  = (blockIdx.x * 256 + threadIdx.x) >> 6;  // 0..4095
    const int lane = threadIdx.x & 63;
    const int b    = wid >> 9;
    const float* xb = xyz + (size_t)b * NPT * 3;

    const float qx = newxyz[wid * 3 + 0];
    const float qy = newxyz[wid * 3 + 1];
    const float qz = newxyz[wid * 3 + 2];
    int* out = gidx + (size_t)wid * NS;

    const float R2 = 0.04f;   // f32(0.2*0.2 in f64); NOT 0.2f*0.2f (1 ulp higher)
    int cnt = 0, first = -1;

    for (int base = 0; base < NPT; base += 64) {
        const int p = base + lane;
        const float dx = __fsub_rn(xb[p * 3 + 0], qx);
        const float dy = __fsub_rn(xb[p * 3 + 1], qy);
        const float dz = __fsub_rn(xb[p * 3 + 2], qz);
        const float d  = __fadd_rn(__fadd_rn(__fmul_rn(dx, dx), __fmul_rn(dy, dy)),
                                   __fmul_rn(dz, dz));
        const bool in = (d <= R2);
        const unsigned long long m = __ballot(in);
        if (first < 0 && m) first = base + (__ffsll((unsigned long long)m) - 1);
        if (in) {
            const int pos = cnt + __popcll(m & ((1ull << lane) - 1ull));
            if (pos < NS) out[pos] = p;
        }
        cnt += __popcll(m);
        if (cnt >= NS) break;
    }
    if (cnt < NS) {
        const int f = (cnt > 0) ? first : (NPT - 1);
        for (int j = cnt + lane; j < NS; j += 64) out[j] = f;
    }
}

// ---------------------------------------------------------------------------
// Kernel 3: gather + 3-layer MLP (BN folded) + max over the 32 samples.
// One block per (b,s). Weights staged per-layer in a shared 34.8KB region.
// Channel layout permuted: [feat(64) | xyz-diff(3) | pad] for aligned float4.
// ---------------------------------------------------------------------------
template <int OP>
__device__ inline void mlp_layer(const float* __restrict__ inb,
                                 const float* __restrict__ wbuf,
                                 const float* __restrict__ scp,
                                 const float* __restrict__ bip,
                                 float* __restrict__ outb, int nchunk, int t)
{
    const int ko = t & 15;
    const int og = t >> 4;
    const int o0 = og * OP;
    float acc0[OP], acc1[OP];
#pragma unroll
    for (int j = 0; j < OP; ++j) { acc0[j] = 0.f; acc1[j] = 0.f; }

    for (int cc = 0; cc < nchunk; ++cc) {
        const int c = cc * 4;
        const float4 xa = *(const float4*)(inb + ko * 68 + c);
        const float4 xb = *(const float4*)(inb + (ko + 16) * 68 + c);
#pragma unroll
        for (int j = 0; j < OP; ++j) {
            const float4 w = *(const float4*)(wbuf + (o0 + j) * 68 + c);
            acc0[j] += xa.x * w.x + xa.y * w.y + xa.z * w.z + xa.w * w.w;
            acc1[j] += xb.x * w.x + xb.y * w.y + xb.z * w.z + xb.w * w.w;
        }
    }
#pragma unroll
    for (int j = 0; j < OP; ++j) {
        const float sv = scp[o0 + j], bv = bip[o0 + j];
        acc0[j] = fmaxf(acc0[j] * sv + bv, 0.f);
        acc1[j] = fmaxf(acc1[j] * sv + bv, 0.f);
    }
#pragma unroll
    for (int jb = 0; jb < OP; jb += 4) {
        *(float4*)(outb + ko * 68 + o0 + jb) =
            make_float4(acc0[jb], acc0[jb + 1], acc0[jb + 2], acc0[jb + 3]);
        *(float4*)(outb + (ko + 16) * 68 + o0 + jb) =
            make_float4(acc1[jb], acc1[jb + 1], acc1[jb + 2], acc1[jb + 3]);
    }
}

__device__ inline void mlp_layer2(const float* __restrict__ inb,
                                  const float* __restrict__ wbuf,
                                  const float* __restrict__ scp,
                                  const float* __restrict__ bip,
                                  float* __restrict__ out, int b, int s, int t)
{
    const int ko = t & 15;
    const int og = t >> 4;
    const int o0 = og * 8;
    float acc0[8], acc1[8];
#pragma unroll
    for (int j = 0; j < 8; ++j) { acc0[j] = 0.f; acc1[j] = 0.f; }

    for (int cc = 0; cc < 16; ++cc) {
        const int c = cc * 4;
        const float4 xa = *(const float4*)(inb + ko * 68 + c);
        const float4 xb = *(const float4*)(inb + (ko + 16) * 68 + c);
#pragma unroll
        for (int j = 0; j < 8; ++j) {
            const float4 w = *(const float4*)(wbuf + (o0 + j) * 68 + c);
            acc0[j] += xa.x * w.x + xa.y * w.y + xa.z * w.z + xa.w * w.w;
            acc1[j] += xb.x * w.x + xb.y * w.y + xb.z * w.z + xb.w * w.w;
        }
    }
    float v[8];
#pragma unroll
    for (int j = 0; j < 8; ++j) {
        const float sv = scp[o0 + j], bv = bip[o0 + j];
        const float h0 = fmaxf(acc0[j] * sv + bv, 0.f);
        const float h1 = fmaxf(acc1[j] * sv + bv, 0.f);
        v[j] = fmaxf(h0, h1);
    }
#pragma unroll
    for (int m = 1; m <= 8; m <<= 1) {
#pragma unroll
        for (int j = 0; j < 8; ++j) v[j] = fmaxf(v[j], __shfl_xor(v[j], m, 64));
    }
    if (ko == 0) {
#pragma unroll
        for (int j = 0; j < 8; ++j)
            out[((size_t)b * 128 + o0 + j) * NQ + s] = v[j];
    }
}

__global__ __launch_bounds__(256) void mlp_kernel(
    const float* __restrict__ xyz, const float* __restrict__ feat,
    const float* __restrict__ newxyz, const int* __restrict__ gidx,
    const float* __restrict__ w0, const float* __restrict__ g0,
    const float* __restrict__ b0, const float* __restrict__ m0,
    const float* __restrict__ v0,
    const float* __restrict__ w1, const float* __restrict__ g1,
    const float* __restrict__ b1, const float* __restrict__ m1,
    const float* __restrict__ v1,
    const float* __restrict__ w2, const float* __restrict__ g2,
    const float* __restrict__ b2, const float* __restrict__ m2,
    const float* __restrict__ v2,
    float* __restrict__ out)
{
    __shared__ float wbuf[128 * 68];   // 34816 B
    __shared__ float bufA[32 * 68];    //  8704 B
    __shared__ float bufB[32 * 68];    //  8704 B
    __shared__ float sc[256], bi[256]; //  2048 B   -> total 54272 B

    const int t   = threadIdx.x;
    const int grp = blockIdx.x;       // 0..4095
    const int b   = grp >> 9;
    const int s   = grp & (NQ - 1);
    const int* gi = gidx + (size_t)grp * NS;

    // folded BN params for all three layers
    if (t < 64) {
        const float sv = g0[t] * rsqrtf(v0[t] + 1e-5f);
        sc[t] = sv; bi[t] = b0[t] - m0[t] * sv;
    } else if (t < 128) {
        const int j = t - 64;
        const float sv = g1[j] * rsqrtf(v1[j] + 1e-5f);
        sc[t] = sv; bi[t] = b1[j] - m1[j] * sv;
    } else {
        const int j = t - 128;
        const float sv = g2[j] * rsqrtf(v2[j] + 1e-5f);
        sc[t] = sv; bi[t] = b2[j] - m2[j] * sv;
    }

    // layer-0 weights, channel-permuted: [feat 0..63 | xyz 64..66 | 0]
    for (int i = t; i < 64 * 68; i += 256) {
        const int o = i / 68, c = i - o * 68;
        float v;
        if (c < 64)       v = w0[o * 67 + 3 + c];
        else if (c < 67)  v = w0[o * 67 + (c - 64)];
        else              v = 0.f;
        wbuf[i] = v;
    }

    // gather x into bufA: feat then xyz-diff
    {
        const int k = t >> 3, f = t & 7;
        const int p = gi[k];
        const float* fr = feat + ((size_t)b * NPT + p) * 64 + f * 8;
        const float4 a0 = *(const float4*)fr;
        const float4 a1 = *(const float4*)(fr + 4);
        *(float4*)(bufA + k * 68 + f * 8)     = a0;
        *(float4*)(bufA + k * 68 + f * 8 + 4) = a1;
        if (f == 0) {
            const float qx = newxyz[grp * 3 + 0];
            const float qy = newxyz[grp * 3 + 1];
            const float qz = newxyz[grp * 3 + 2];
            const float* xp = xyz + ((size_t)b * NPT + p) * 3;
            bufA[k * 68 + 64] = xp[0] - qx;
            bufA[k * 68 + 65] = xp[1] - qy;
            bufA[k * 68 + 66] = xp[2] - qz;
            bufA[k * 68 + 67] = 0.f;
        }
    }
    __syncthreads();

    mlp_layer<4>(bufA, wbuf, sc, bi, bufB, 17, t);
    __syncthreads();

    for (int i = t; i < 64 * 68; i += 256) {
        const int o = i / 68, c = i - o * 68;
        wbuf[i] = (c < 64) ? w1[o * 64 + c] : 0.f;
    }
    __syncthreads();

    mlp_layer<4>(bufB, wbuf, sc + 64, bi + 64, bufA, 16, t);
    __syncthreads();

    for (int i = t; i < 128 * 68; i += 256) {
        const int o = i / 68, c = i - o * 68;
        wbuf[i] = (c < 64) ? w2[o * 64 + c] : 0.f;
    }
    __syncthreads();

    mlp_layer2(bufA, wbuf, sc + 128, bi + 128, out, b, s, t);
}

// ---------------------------------------------------------------------------
extern "C" void kernel_launch(void* const* d_in, const int* in_sizes, int n_in,
                              void* d_out, int out_size, void* d_ws, size_t ws_size,
                              hipStream_t stream)
{
    const float* xyz  = (const float*)d_in[0];
    const float* feat = (const float*)d_in[1];
    const float* w0 = (const float*)d_in[2];
    const float* g0 = (const float*)d_in[3];
    const float* b0 = (const float*)d_in[4];
    const float* m0 = (const float*)d_in[5];
    const float* v0 = (const float*)d_in[6];
    const float* w1 = (const float*)d_in[7];
    const float* g1 = (const float*)d_in[8];
    const float* b1 = (const float*)d_in[9];
    const float* m1 = (const float*)d_in[10];
    const float* v1 = (const float*)d_in[11];
    const float* w2 = (const float*)d_in[12];
    const float* g2 = (const float*)d_in[13];
    const float* b2 = (const float*)d_in[14];
    const float* m2 = (const float*)d_in[15];
    const float* v2 = (const float*)d_in[16];

    float* out      = (float*)d_out;
    float* new_xyz  = out;                      // 8*512*3 = 12288 floats
    float* out_feat = out + BATCH * NQ * 3;     // 8*128*512 floats
    int*   gidx     = (int*)d_ws;               // 4096*32 ints = 512 KB

    fps_kernel<<<BATCH, 1024, 0, stream>>>(xyz, new_xyz);
    bq_kernel<<<(BATCH * NQ * 64) / 256, 256, 0, stream>>>(xyz, new_xyz, gidx);
    mlp_kernel<<<BATCH * NQ, 256, 0, stream>>>(xyz, feat, new_xyz, gidx,
                                               w0, g0, b0, m0, v0,
                                               w1, g1, b1, m1, v1,
                                               w2, g2, b2, m2, v2,
                                               out_feat);
}

// Round 2
// 1446.081 us; speedup vs baseline: 1.0363x; 1.0363x over previous
//
#include <hip/hip_runtime.h>
#include <hip/hip_bf16.h>

#define NPT   16384
#define NQ    512
#define NS    32
#define BATCH 8

typedef float f32x2 __attribute__((ext_vector_type(2)));

// ---------------------------------------------------------------------------
// DPP helpers: move a u64 across lanes (both 32-bit halves), invalid lanes -> 0
// (0 is the identity for our max since every real key > 0).
// ---------------------------------------------------------------------------
template <int CTRL>
__device__ inline unsigned long long dpp_u64(unsigned long long x)
{
    int lo = (int)(unsigned)x;
    int hi = (int)(unsigned)(x >> 32);
    lo = __builtin_amdgcn_update_dpp(0, lo, CTRL, 0xf, 0xf, true);
    hi = __builtin_amdgcn_update_dpp(0, hi, CTRL, 0xf, 0xf, true);
    return ((unsigned long long)(unsigned)hi << 32) | (unsigned)lo;
}

__device__ inline unsigned long long max64(unsigned long long a, unsigned long long b)
{
    return a > b ? a : b;
}

// ---------------------------------------------------------------------------
// Kernel 1: furthest point sampling. One block per batch, 1024 threads,
// 16 points per thread (8 float2 pairs) in registers. Packed-fp32 (v_pk_*)
// distance update — bit-exact rn semantics, contraction disabled. Wave
// reduction via DPP row_shr/row_bcast (result lands in lane 63), then a
// 16-entry LDS scan across waves. First-occurrence argmax via packed
// (dist_bits<<32)|~idx key.
// ---------------------------------------------------------------------------
__global__ __launch_bounds__(1024) void fps_kernel(const float* __restrict__ xyz,
                                                   float* __restrict__ new_xyz)
{
#pragma clang fp contract(off)
    const int b = blockIdx.x;
    const int t = threadIdx.x;
    const float* xb = xyz + (size_t)b * NPT * 3;

    f32x2 xr[8], yr[8], zr[8], dr[8];
    const float INF = __int_as_float(0x7f800000);
#pragma unroll
    for (int j = 0; j < 8; ++j) {
        const int p0 = (2 * j) * 1024 + t;
        const int p1 = (2 * j + 1) * 1024 + t;
        xr[j] = (f32x2){xb[p0 * 3 + 0], xb[p1 * 3 + 0]};
        yr[j] = (f32x2){xb[p0 * 3 + 1], xb[p1 * 3 + 1]};
        zr[j] = (f32x2){xb[p0 * 3 + 2], xb[p1 * 3 + 2]};
        dr[j] = (f32x2){INF, INF};
    }

    __shared__ unsigned long long red[2][16];

    float px = xb[0], py = xb[1], pz = xb[2];

    for (int s = 0; s < NQ; ++s) {
        if (t == 0) {
            float* o = new_xyz + ((size_t)b * NQ + s) * 3;
            o[0] = px; o[1] = py; o[2] = pz;
        }
        if (s == NQ - 1) break;

        // --- packed distance update + local argmax over 16 points ---------
        const f32x2 pxv = {px, px}, pyv = {py, py}, pzv = {pz, pz};
        float dmax = -1.0f;
        int   bi_  = 0;
#pragma unroll
        for (int j = 0; j < 8; ++j) {
            const f32x2 dx = xr[j] - pxv;
            const f32x2 dy = yr[j] - pyv;
            const f32x2 dz = zr[j] - pzv;
            f32x2 d = (dx * dx + dy * dy);       // pk_mul, pk_mul, pk_add (no fma!)
            d = d + dz * dz;                     // pk_mul, pk_add
            const f32x2 dn = __builtin_elementwise_min(dr[j], d);
            dr[j] = dn;
            // within pair: .x has the smaller global index -> wins ties
            const float ds = (dn.x >= dn.y) ? dn.x : dn.y;
            const int   is = (dn.x >= dn.y) ? (2 * j) : (2 * j + 1);
            // across pairs ascending j: strict > keeps first occurrence
            if (ds > dmax) { dmax = ds; bi_ = is; }
        }

        const unsigned pidx = (unsigned)(bi_ * 1024 + t);
        unsigned long long k =
            ((unsigned long long)__float_as_uint(dmax) << 32) | (unsigned)(~pidx);

        // --- wave max via DPP (inclusive-scan pattern; lane 63 = wave max) -
        k = max64(k, dpp_u64<0x111>(k));   // row_shr:1
        k = max64(k, dpp_u64<0x112>(k));   // row_shr:2
        k = max64(k, dpp_u64<0x114>(k));   // row_shr:4
        k = max64(k, dpp_u64<0x118>(k));   // row_shr:8
        k = max64(k, dpp_u64<0x142>(k));   // row_bcast:15
        k = max64(k, dpp_u64<0x143>(k));   // row_bcast:31

        if ((t & 63) == 63) red[s & 1][t >> 6] = k;
        __syncthreads();

        unsigned long long best = red[s & 1][0];
#pragma unroll
        for (int w = 1; w < 16; ++w) {
            const unsigned long long o = red[s & 1][w];
            if (o > best) best = o;
        }
        const int nxt = (int)(~(unsigned)best);
        px = xb[nxt * 3 + 0];
        py = xb[nxt * 3 + 1];
        pz = xb[nxt * 3 + 2];
    }
}

// ---------------------------------------------------------------------------
// Kernel 2: ball query. One wave per (b,s) query; ascending index scan with
// ballot + prefix popcount collects exactly the 32 smallest in-radius indices.
// ---------------------------------------------------------------------------
__global__ __launch_bounds__(256) void bq_kernel(const float* __restrict__ xyz,
                                                 const float* __restrict__ newxyz,
                                                 int* __restrict__ gidx)
{
    const int wid  = (blockIdx.x * 256 + threadIdx.x) >> 6;  // 0..4095
    const int lane = threadIdx.x & 63;
    const int b    = wid >> 9;
    const float* xb = xyz + (size_t)b * NPT * 3;

    const float qx = newxyz[wid * 3 + 0];
    const float qy = newxyz[wid * 3 + 1];
    const float qz = newxyz[wid * 3 + 2];
    int* out = gidx + (size_t)wid * NS;

    const float R2 = 0.04f;   // f32(0.2*0.2 in f64); NOT 0.2f*0.2f (1 ulp higher)
    int cnt = 0, first = -1;

    for (int base = 0; base < NPT; base += 64) {
        const int p = base + lane;
        const float dx = __fsub_rn(xb[p * 3 + 0], qx);
        const float dy = __fsub_rn(xb[p * 3 + 1], qy);
        const float dz = __fsub_rn(xb[p * 3 + 2], qz);
        const float d  = __fadd_rn(__fadd_rn(__fmul_rn(dx, dx), __fmul_rn(dy, dy)),
                                   __fmul_rn(dz, dz));
        const bool in = (d <= R2);
        const unsigned long long m = __ballot(in);
        if (first < 0 && m) first = base + (__ffsll((unsigned long long)m) - 1);
        if (in) {
            const int pos = cnt + __popcll(m & ((1ull << lane) - 1ull));
            if (pos < NS) out[pos] = p;
        }
        cnt += __popcll(m);
        if (cnt >= NS) break;
    }
    if (cnt < NS) {
        const int f = (cnt > 0) ? first : (NPT - 1);
        for (int j = cnt + lane; j < NS; j += 64) out[j] = f;
    }
}

// ---------------------------------------------------------------------------
// Kernel 3: gather + 3-layer MLP (BN folded) + max over the 32 samples.
// One block per (b,s). Weights staged per-layer in a shared 34.8KB region.
// Channel layout permuted: [feat(64) | xyz-diff(3) | pad] for aligned float4.
// ---------------------------------------------------------------------------
template <int OP>
__device__ inline void mlp_layer(const float* __restrict__ inb,
                                 const float* __restrict__ wbuf,
                                 const float* __restrict__ scp,
                                 const float* __restrict__ bip,
                                 float* __restrict__ outb, int nchunk, int t)
{
    const int ko = t & 15;
    const int og = t >> 4;
    const int o0 = og * OP;
    float acc0[OP], acc1[OP];
#pragma unroll
    for (int j = 0; j < OP; ++j) { acc0[j] = 0.f; acc1[j] = 0.f; }

    for (int cc = 0; cc < nchunk; ++cc) {
        const int c = cc * 4;
        const float4 xa = *(const float4*)(inb + ko * 68 + c);
        const float4 xb = *(const float4*)(inb + (ko + 16) * 68 + c);
#pragma unroll
        for (int j = 0; j < OP; ++j) {
            const float4 w = *(const float4*)(wbuf + (o0 + j) * 68 + c);
            acc0[j] += xa.x * w.x + xa.y * w.y + xa.z * w.z + xa.w * w.w;
            acc1[j] += xb.x * w.x + xb.y * w.y + xb.z * w.z + xb.w * w.w;
        }
    }
#pragma unroll
    for (int j = 0; j < OP; ++j) {
        const float sv = scp[o0 + j], bv = bip[o0 + j];
        acc0[j] = fmaxf(acc0[j] * sv + bv, 0.f);
        acc1[j] = fmaxf(acc1[j] * sv + bv, 0.f);
    }
#pragma unroll
    for (int jb = 0; jb < OP; jb += 4) {
        *(float4*)(outb + ko * 68 + o0 + jb) =
            make_float4(acc0[jb], acc0[jb + 1], acc0[jb + 2], acc0[jb + 3]);
        *(float4*)(outb + (ko + 16) * 68 + o0 + jb) =
            make_float4(acc1[jb], acc1[jb + 1], acc1[jb + 2], acc1[jb + 3]);
    }
}

__device__ inline void mlp_layer2(const float* __restrict__ inb,
                                  const float* __restrict__ wbuf,
                                  const float* __restrict__ scp,
                                  const float* __restrict__ bip,
                                  float* __restrict__ out, int b, int s, int t)
{
    const int ko = t & 15;
    const int og = t >> 4;
    const int o0 = og * 8;
    float acc0[8], acc1[8];
#pragma unroll
    for (int j = 0; j < 8; ++j) { acc0[j] = 0.f; acc1[j] = 0.f; }

    for (int cc = 0; cc < 16; ++cc) {
        const int c = cc * 4;
        const float4 xa = *(const float4*)(inb + ko * 68 + c);
        const float4 xb = *(const float4*)(inb + (ko + 16) * 68 + c);
#pragma unroll
        for (int j = 0; j < 8; ++j) {
            const float4 w = *(const float4*)(wbuf + (o0 + j) * 68 + c);
            acc0[j] += xa.x * w.x + xa.y * w.y + xa.z * w.z + xa.w * w.w;
            acc1[j] += xb.x * w.x + xb.y * w.y + xb.z * w.z + xb.w * w.w;
        }
    }
    float v[8];
#pragma unroll
    for (int j = 0; j < 8; ++j) {
        const float sv = scp[o0 + j], bv = bip[o0 + j];
        const float h0 = fmaxf(acc0[j] * sv + bv, 0.f);
        const float h1 = fmaxf(acc1[j] * sv + bv, 0.f);
        v[j] = fmaxf(h0, h1);
    }
#pragma unroll
    for (int m = 1; m <= 8; m <<= 1) {
#pragma unroll
        for (int j = 0; j < 8; ++j) v[j] = fmaxf(v[j], __shfl_xor(v[j], m, 64));
    }
    if (ko == 0) {
#pragma unroll
        for (int j = 0; j < 8; ++j)
            out[((size_t)b * 128 + o0 + j) * NQ + s] = v[j];
    }
}

__global__ __launch_bounds__(256) void mlp_kernel(
    const float* __restrict__ xyz, const float* __restrict__ feat,
    const float* __restrict__ newxyz, const int* __restrict__ gidx,
    const float* __restrict__ w0, const float* __restrict__ g0,
    const float* __restrict__ b0, const float* __restrict__ m0,
    const float* __restrict__ v0,
    const float* __restrict__ w1, const float* __restrict__ g1,
    const float* __restrict__ b1, const float* __restrict__ m1,
    const float* __restrict__ v1,
    const float* __restrict__ w2, const float* __restrict__ g2,
    const float* __restrict__ b2, const float* __restrict__ m2,
    const float* __restrict__ v2,
    float* __restrict__ out)
{
    __shared__ float wbuf[128 * 68];   // 34816 B
    __shared__ float bufA[32 * 68];    //  8704 B
    __shared__ float bufB[32 * 68];    //  8704 B
    __shared__ float sc[256], bi[256]; //  2048 B   -> total 54272 B

    const int t   = threadIdx.x;
    const int grp = blockIdx.x;       // 0..4095
    const int b   = grp >> 9;
    const int s   = grp & (NQ - 1);
    const int* gi = gidx + (size_t)grp * NS;

    // folded BN params for all three layers
    if (t < 64) {
        const float sv = g0[t] * rsqrtf(v0[t] + 1e-5f);
        sc[t] = sv; bi[t] = b0[t] - m0[t] * sv;
    } else if (t < 128) {
        const int j = t - 64;
        const float sv = g1[j] * rsqrtf(v1[j] + 1e-5f);
        sc[t] = sv; bi[t] = b1[j] - m1[j] * sv;
    } else {
        const int j = t - 128;
        const float sv = g2[j] * rsqrtf(v2[j] + 1e-5f);
        sc[t] = sv; bi[t] = b2[j] - m2[j] * sv;
    }

    // layer-0 weights, channel-permuted: [feat 0..63 | xyz 64..66 | 0]
    for (int i = t; i < 64 * 68; i += 256) {
        const int o = i / 68, c = i - o * 68;
        float v;
        if (c < 64)       v = w0[o * 67 + 3 + c];
        else if (c < 67)  v = w0[o * 67 + (c - 64)];
        else              v = 0.f;
        wbuf[i] = v;
    }

    // gather x into bufA: feat then xyz-diff
    {
        const int k = t >> 3, f = t & 7;
        const int p = gi[k];
        const float* fr = feat + ((size_t)b * NPT + p) * 64 + f * 8;
        const float4 a0 = *(const float4*)fr;
        const float4 a1 = *(const float4*)(fr + 4);
        *(float4*)(bufA + k * 68 + f * 8)     = a0;
        *(float4*)(bufA + k * 68 + f * 8 + 4) = a1;
        if (f == 0) {
            const float qx = newxyz[grp * 3 + 0];
            const float qy = newxyz[grp * 3 + 1];
            const float qz = newxyz[grp * 3 + 2];
            const float* xp = xyz + ((size_t)b * NPT + p) * 3;
            bufA[k * 68 + 64] = xp[0] - qx;
            bufA[k * 68 + 65] = xp[1] - qy;
            bufA[k * 68 + 66] = xp[2] - qz;
            bufA[k * 68 + 67] = 0.f;
        }
    }
    __syncthreads();

    mlp_layer<4>(bufA, wbuf, sc, bi, bufB, 17, t);
    __syncthreads();

    for (int i = t; i < 64 * 68; i += 256) {
        const int o = i / 68, c = i - o * 68;
        wbuf[i] = (c < 64) ? w1[o * 64 + c] : 0.f;
    }
    __syncthreads();

    mlp_layer<4>(bufB, wbuf, sc + 64, bi + 64, bufA, 16, t);
    __syncthreads();

    for (int i = t; i < 128 * 68; i += 256) {
        const int o = i / 68, c = i - o * 68;
        wbuf[i] = (c < 64) ? w2[o * 64 + c] : 0.f;
    }
    __syncthreads();

    mlp_layer2(bufA, wbuf, sc + 128, bi + 128, out, b, s, t);
}

// ---------------------------------------------------------------------------
extern "C" void kernel_launch(void* const* d_in, const int* in_sizes, int n_in,
                              void* d_out, int out_size, void* d_ws, size_t ws_size,
                              hipStream_t stream)
{
    const float* xyz  = (const float*)d_in[0];
    const float* feat = (const float*)d_in[1];
    const float* w0 = (const float*)d_in[2];
    const float* g0 = (const float*)d_in[3];
    const float* b0 = (const float*)d_in[4];
    const float* m0 = (const float*)d_in[5];
    const float* v0 = (const float*)d_in[6];
    const float* w1 = (const float*)d_in[7];
    const float* g1 = (const float*)d_in[8];
    const float* b1 = (const float*)d_in[9];
    const float* m1 = (const float*)d_in[10];
    const float* v1 = (const float*)d_in[11];
    const float* w2 = (const float*)d_in[12];
    const float* g2 = (const float*)d_in[13];
    const float* b2 = (const float*)d_in[14];
    const float* m2 = (const float*)d_in[15];
    const float* v2 = (const float*)d_in[16];

    float* out      = (float*)d_out;
    float* new_xyz  = out;                      // 8*512*3 = 12288 floats
    float* out_feat = out + BATCH * NQ * 3;     // 8*128*512 floats
    int*   gidx     = (int*)d_ws;               // 4096*32 ints = 512 KB

    fps_kernel<<<BATCH, 1024, 0, stream>>>(xyz, new_xyz);
    bq_kernel<<<(BATCH * NQ * 64) / 256, 256, 0, stream>>>(xyz, new_xyz, gidx);
    mlp_kernel<<<BATCH * NQ, 256, 0, stream>>>(xyz, feat, new_xyz, gidx,
                                               w0, g0, b0, m0, v0,
                                               w1, g1, b1, m1, v1,
                                               w2, g2, b2, m2, v2,
                                               out_feat);
}

// Round 3
// 1138.560 us; speedup vs baseline: 1.3162x; 1.2701x over previous
//
#include <hip/hip_runtime.h>
#include <hip/hip_bf16.h>

#define NPT   16384
#define NQ    512
#define NS    32
#define BATCH 8

typedef float f32x2 __attribute__((ext_vector_type(2)));

// ---------------------------------------------------------------------------
// DPP helper on a 64-bit value (two 32-bit halves), invalid lanes -> 0.
// 0 is the identity for our max since every real key > 0.
// Keys are (dist_bits<<32)|~idx with dist in [0,3] -> as f64 bit patterns they
// are positive, finite, never NaN; for positive doubles value order == bit
// order and CDNA never flushes f64 denormals, so v_max_f64 == exact u64 max.
// ---------------------------------------------------------------------------
template <int CTRL>
__device__ inline double dpp_f64(double x)
{
    const unsigned long long u = (unsigned long long)__double_as_longlong(x);
    int lo = (int)(unsigned)u;
    int hi = (int)(unsigned)(u >> 32);
    lo = __builtin_amdgcn_update_dpp(0, lo, CTRL, 0xf, 0xf, true);
    hi = __builtin_amdgcn_update_dpp(0, hi, CTRL, 0xf, 0xf, true);
    return __longlong_as_double(
        (long long)(((unsigned long long)(unsigned)hi << 32) | (unsigned)lo));
}

// ---------------------------------------------------------------------------
// Kernel 1: furthest point sampling. One block per batch, 1024 threads,
// 16 points per thread (8 float2 pairs) in registers. waves_per_eu(4,4)
// pins the register budget at 128/wave so coords stay in arch VGPRs.
// Reduction: 6-stage DPP wave max (v_max_f64 keys) -> 16 LDS slots ->
// lane-parallel DPP combine -> readlane(15) -> scalar coord fetch.
// ---------------------------------------------------------------------------
__global__ __launch_bounds__(1024)
__attribute__((amdgpu_waves_per_eu(4, 4)))
void fps_kernel(const float* __restrict__ xyz, float* __restrict__ new_xyz)
{
#pragma clang fp contract(off)
    const int b = blockIdx.x;
    const int t = threadIdx.x;
    const float* xb = xyz + (size_t)b * NPT * 3;

    f32x2 xr[8], yr[8], zr[8], dr[8];
    const float INF = __int_as_float(0x7f800000);
#pragma unroll
    for (int j = 0; j < 8; ++j) {
        const int p0 = (2 * j) * 1024 + t;
        const int p1 = (2 * j + 1) * 1024 + t;
        xr[j] = (f32x2){xb[p0 * 3 + 0], xb[p1 * 3 + 0]};
        yr[j] = (f32x2){xb[p0 * 3 + 1], xb[p1 * 3 + 1]};
        zr[j] = (f32x2){xb[p0 * 3 + 2], xb[p1 * 3 + 2]};
        dr[j] = (f32x2){INF, INF};
    }

    __shared__ unsigned long long red[2][16];

    float px = xb[0], py = xb[1], pz = xb[2];

    for (int s = 0; s < NQ; ++s) {
        if (t == 0) {
            float* o = new_xyz + ((size_t)b * NQ + s) * 3;
            o[0] = px; o[1] = py; o[2] = pz;
        }
        if (s == NQ - 1) break;

        // --- packed distance update + local argmax over 16 points ---------
        const f32x2 pxv = {px, px}, pyv = {py, py}, pzv = {pz, pz};
        float dmax = -1.0f;
        int   bi_  = 0;
#pragma unroll
        for (int j = 0; j < 8; ++j) {
            const f32x2 dx = xr[j] - pxv;
            const f32x2 dy = yr[j] - pyv;
            const f32x2 dz = zr[j] - pzv;
            f32x2 d = (dx * dx + dy * dy);       // rn mul/add, no fma
            d = d + dz * dz;
            const f32x2 dn = __builtin_elementwise_min(dr[j], d);
            dr[j] = dn;
            // within pair: .x has the smaller global index -> wins ties
            const float ds = (dn.x >= dn.y) ? dn.x : dn.y;
            const int   is = (dn.x >= dn.y) ? (2 * j) : (2 * j + 1);
            // across pairs ascending j: strict > keeps first occurrence
            if (ds > dmax) { dmax = ds; bi_ = is; }
        }

        const unsigned pidx = (unsigned)(bi_ * 1024 + t);
        double kd = __longlong_as_double((long long)(
            ((unsigned long long)__float_as_uint(dmax) << 32) | (unsigned)(~pidx)));

        // --- wave max via DPP; lane 63 = wave max -------------------------
        kd = fmax(kd, dpp_f64<0x111>(kd));   // row_shr:1
        kd = fmax(kd, dpp_f64<0x112>(kd));   // row_shr:2
        kd = fmax(kd, dpp_f64<0x114>(kd));   // row_shr:4
        kd = fmax(kd, dpp_f64<0x118>(kd));   // row_shr:8
        kd = fmax(kd, dpp_f64<0x142>(kd));   // row_bcast:15
        kd = fmax(kd, dpp_f64<0x143>(kd));   // row_bcast:31

        if ((t & 63) == 63)
            red[s & 1][t >> 6] = (unsigned long long)__double_as_longlong(kd);
        __syncthreads();

        // --- cross-wave combine: slot = lane&15, 4 DPP stages -------------
        double kc = __longlong_as_double((long long)red[s & 1][t & 15]);
        kc = fmax(kc, dpp_f64<0x111>(kc));
        kc = fmax(kc, dpp_f64<0x112>(kc));
        kc = fmax(kc, dpp_f64<0x114>(kc));
        kc = fmax(kc, dpp_f64<0x118>(kc));   // lane 15 of each row = global max

        const unsigned long long kw = (unsigned long long)__double_as_longlong(kc);
        const unsigned lo15 = (unsigned)__builtin_amdgcn_readlane((int)(unsigned)kw, 15);
        const int nxt = (int)(unsigned)(~lo15);   // uniform (SGPR)

        px = xb[nxt * 3 + 0];
        py = xb[nxt * 3 + 1];
        pz = xb[nxt * 3 + 2];
    }
}

// ---------------------------------------------------------------------------
// Kernel 2: ball query. One wave per (b,s) query; ascending index scan with
// ballot + prefix popcount collects exactly the 32 smallest in-radius indices.
// ---------------------------------------------------------------------------
__global__ __launch_bounds__(256) void bq_kernel(const float* __restrict__ xyz,
                                                 const float* __restrict__ newxyz,
                                                 int* __restrict__ gidx)
{
    const int wid  = (blockIdx.x * 256 + threadIdx.x) >> 6;  // 0..4095
    const int lane = threadIdx.x & 63;
    const int b    = wid >> 9;
    const float* xb = xyz + (size_t)b * NPT * 3;

    const float qx = newxyz[wid * 3 + 0];
    const float qy = newxyz[wid * 3 + 1];
    const float qz = newxyz[wid * 3 + 2];
    int* out = gidx + (size_t)wid * NS;

    const float R2 = 0.04f;   // f32(0.2*0.2 in f64); NOT 0.2f*0.2f (1 ulp higher)
    int cnt = 0, first = -1;

    for (int base = 0; base < NPT; base += 64) {
        const int p = base + lane;
        const float dx = __fsub_rn(xb[p * 3 + 0], qx);
        const float dy = __fsub_rn(xb[p * 3 + 1], qy);
        const float dz = __fsub_rn(xb[p * 3 + 2], qz);
        const float d  = __fadd_rn(__fadd_rn(__fmul_rn(dx, dx), __fmul_rn(dy, dy)),
                                   __fmul_rn(dz, dz));
        const bool in = (d <= R2);
        const unsigned long long m = __ballot(in);
        if (first < 0 && m) first = base + (__ffsll((unsigned long long)m) - 1);
        if (in) {
            const int pos = cnt + __popcll(m & ((1ull << lane) - 1ull));
            if (pos < NS) out[pos] = p;
        }
        cnt += __popcll(m);
        if (cnt >= NS) break;
    }
    if (cnt < NS) {
        const int f = (cnt > 0) ? first : (NPT - 1);
        for (int j = cnt + lane; j < NS; j += 64) out[j] = f;
    }
}

// ---------------------------------------------------------------------------
// Kernel 3: gather + 3-layer MLP (BN folded) + max over the 32 samples.
// One block per (b,s). Weights staged per-layer in a shared 34.8KB region.
// Channel layout permuted: [feat(64) | xyz-diff(3) | pad] for aligned float4.
// ---------------------------------------------------------------------------
template <int OP>
__device__ inline void mlp_layer(const float* __restrict__ inb,
                                 const float* __restrict__ wbuf,
                                 const float* __restrict__ scp,
                                 const float* __restrict__ bip,
                                 float* __restrict__ outb, int nchunk, int t)
{
    const int ko = t & 15;
    const int og = t >> 4;
    const int o0 = og * OP;
    float acc0[OP], acc1[OP];
#pragma unroll
    for (int j = 0; j < OP; ++j) { acc0[j] = 0.f; acc1[j] = 0.f; }

    for (int cc = 0; cc < nchunk; ++cc) {
        const int c = cc * 4;
        const float4 xa = *(const float4*)(inb + ko * 68 + c);
        const float4 xb = *(const float4*)(inb + (ko + 16) * 68 + c);
#pragma unroll
        for (int j = 0; j < OP; ++j) {
            const float4 w = *(const float4*)(wbuf + (o0 + j) * 68 + c);
            acc0[j] += xa.x * w.x + xa.y * w.y + xa.z * w.z + xa.w * w.w;
            acc1[j] += xb.x * w.x + xb.y * w.y + xb.z * w.z + xb.w * w.w;
        }
    }
#pragma unroll
    for (int j = 0; j < OP; ++j) {
        const float sv = scp[o0 + j], bv = bip[o0 + j];
        acc0[j] = fmaxf(acc0[j] * sv + bv, 0.f);
        acc1[j] = fmaxf(acc1[j] * sv + bv, 0.f);
    }
#pragma unroll
    for (int jb = 0; jb < OP; jb += 4) {
        *(float4*)(outb + ko * 68 + o0 + jb) =
            make_float4(acc0[jb], acc0[jb + 1], acc0[jb + 2], acc0[jb + 3]);
        *(float4*)(outb + (ko + 16) * 68 + o0 + jb) =
            make_float4(acc1[jb], acc1[jb + 1], acc1[jb + 2], acc1[jb + 3]);
    }
}

__device__ inline void mlp_layer2(const float* __restrict__ inb,
                                  const float* __restrict__ wbuf,
                                  const float* __restrict__ scp,
                                  const float* __restrict__ bip,
                                  float* __restrict__ out, int b, int s, int t)
{
    const int ko = t & 15;
    const int og = t >> 4;
    const int o0 = og * 8;
    float acc0[8], acc1[8];
#pragma unroll
    for (int j = 0; j < 8; ++j) { acc0[j] = 0.f; acc1[j] = 0.f; }

    for (int cc = 0; cc < 16; ++cc) {
        const int c = cc * 4;
        const float4 xa = *(const float4*)(inb + ko * 68 + c);
        const float4 xb = *(const float4*)(inb + (ko + 16) * 68 + c);
#pragma unroll
        for (int j = 0; j < 8; ++j) {
            const float4 w = *(const float4*)(wbuf + (o0 + j) * 68 + c);
            acc0[j] += xa.x * w.x + xa.y * w.y + xa.z * w.z + xa.w * w.w;
            acc1[j] += xb.x * w.x + xb.y * w.y + xb.z * w.z + xb.w * w.w;
        }
    }
    float v[8];
#pragma unroll
    for (int j = 0; j < 8; ++j) {
        const float sv = scp[o0 + j], bv = bip[o0 + j];
        const float h0 = fmaxf(acc0[j] * sv + bv, 0.f);
        const float h1 = fmaxf(acc1[j] * sv + bv, 0.f);
        v[j] = fmaxf(h0, h1);
    }
#pragma unroll
    for (int m = 1; m <= 8; m <<= 1) {
#pragma unroll
        for (int j = 0; j < 8; ++j) v[j] = fmaxf(v[j], __shfl_xor(v[j], m, 64));
    }
    if (ko == 0) {
#pragma unroll
        for (int j = 0; j < 8; ++j)
            out[((size_t)b * 128 + o0 + j) * NQ + s] = v[j];
    }
}

__global__ __launch_bounds__(256) void mlp_kernel(
    const float* __restrict__ xyz, const float* __restrict__ feat,
    const float* __restrict__ newxyz, const int* __restrict__ gidx,
    const float* __restrict__ w0, const float* __restrict__ g0,
    const float* __restrict__ b0, const float* __restrict__ m0,
    const float* __restrict__ v0,
    const float* __restrict__ w1, const float* __restrict__ g1,
    const float* __restrict__ b1, const float* __restrict__ m1,
    const float* __restrict__ v1,
    const float* __restrict__ w2, const float* __restrict__ g2,
    const float* __restrict__ b2, const float* __restrict__ m2,
    const float* __restrict__ v2,
    float* __restrict__ out)
{
    __shared__ float wbuf[128 * 68];   // 34816 B
    __shared__ float bufA[32 * 68];    //  8704 B
    __shared__ float bufB[32 * 68];    //  8704 B
    __shared__ float sc[256], bi[256]; //  2048 B   -> total 54272 B

    const int t   = threadIdx.x;
    const int grp = blockIdx.x;       // 0..4095
    const int b   = grp >> 9;
    const int s   = grp & (NQ - 1);
    const int* gi = gidx + (size_t)grp * NS;

    // folded BN params for all three layers
    if (t < 64) {
        const float sv = g0[t] * rsqrtf(v0[t] + 1e-5f);
        sc[t] = sv; bi[t] = b0[t] - m0[t] * sv;
    } else if (t < 128) {
        const int j = t - 64;
        const float sv = g1[j] * rsqrtf(v1[j] + 1e-5f);
        sc[t] = sv; bi[t] = b1[j] - m1[j] * sv;
    } else {
        const int j = t - 128;
        const float sv = g2[j] * rsqrtf(v2[j] + 1e-5f);
        sc[t] = sv; bi[t] = b2[j] - m2[j] * sv;
    }

    // layer-0 weights, channel-permuted: [feat 0..63 | xyz 64..66 | 0]
    for (int i = t; i < 64 * 68; i += 256) {
        const int o = i / 68, c = i - o * 68;
        float v;
        if (c < 64)       v = w0[o * 67 + 3 + c];
        else if (c < 67)  v = w0[o * 67 + (c - 64)];
        else              v = 0.f;
        wbuf[i] = v;
    }

    // gather x into bufA: feat then xyz-diff
    {
        const int k = t >> 3, f = t & 7;
        const int p = gi[k];
        const float* fr = feat + ((size_t)b * NPT + p) * 64 + f * 8;
        const float4 a0 = *(const float4*)fr;
        const float4 a1 = *(const float4*)(fr + 4);
        *(float4*)(bufA + k * 68 + f * 8)     = a0;
        *(float4*)(bufA + k * 68 + f * 8 + 4) = a1;
        if (f == 0) {
            const float qx = newxyz[grp * 3 + 0];
            const float qy = newxyz[grp * 3 + 1];
            const float qz = newxyz[grp * 3 + 2];
            const float* xp = xyz + ((size_t)b * NPT + p) * 3;
            bufA[k * 68 + 64] = xp[0] - qx;
            bufA[k * 68 + 65] = xp[1] - qy;
            bufA[k * 68 + 66] = xp[2] - qz;
            bufA[k * 68 + 67] = 0.f;
        }
    }
    __syncthreads();

    mlp_layer<4>(bufA, wbuf, sc, bi, bufB, 17, t);
    __syncthreads();

    for (int i = t; i < 64 * 68; i += 256) {
        const int o = i / 68, c = i - o * 68;
        wbuf[i] = (c < 64) ? w1[o * 64 + c] : 0.f;
    }
    __syncthreads();

    mlp_layer<4>(bufB, wbuf, sc + 64, bi + 64, bufA, 16, t);
    __syncthreads();

    for (int i = t; i < 128 * 68; i += 256) {
        const int o = i / 68, c = i - o * 68;
        wbuf[i] = (c < 64) ? w2[o * 64 + c] : 0.f;
    }
    __syncthreads();

    mlp_layer2(bufA, wbuf, sc + 128, bi + 128, out, b, s, t);
}

// ---------------------------------------------------------------------------
extern "C" void kernel_launch(void* const* d_in, const int* in_sizes, int n_in,
                              void* d_out, int out_size, void* d_ws, size_t ws_size,
                              hipStream_t stream)
{
    const float* xyz  = (const float*)d_in[0];
    const float* feat = (const float*)d_in[1];
    const float* w0 = (const float*)d_in[2];
    const float* g0 = (const float*)d_in[3];
    const float* b0 = (const float*)d_in[4];
    const float* m0 = (const float*)d_in[5];
    const float* v0 = (const float*)d_in[6];
    const float* w1 = (const float*)d_in[7];
    const float* g1 = (const float*)d_in[8];
    const float* b1 = (const float*)d_in[9];
    const float* m1 = (const float*)d_in[10];
    const float* v1 = (const float*)d_in[11];
    const float* w2 = (const float*)d_in[12];
    const float* g2 = (const float*)d_in[13];
    const float* b2 = (const float*)d_in[14];
    const float* m2 = (const float*)d_in[15];
    const float* v2 = (const float*)d_in[16];

    float* out      = (float*)d_out;
    float* new_xyz  = out;                      // 8*512*3 = 12288 floats
    float* out_feat = out + BATCH * NQ * 3;     // 8*128*512 floats
    int*   gidx     = (int*)d_ws;               // 4096*32 ints = 512 KB

    fps_kernel<<<BATCH, 1024, 0, stream>>>(xyz, new_xyz);
    bq_kernel<<<(BATCH * NQ * 64) / 256, 256, 0, stream>>>(xyz, new_xyz, gidx);
    mlp_kernel<<<BATCH * NQ, 256, 0, stream>>>(xyz, feat, new_xyz, gidx,
                                               w0, g0, b0, m0, v0,
                                               w1, g1, b1, m1, v1,
                                               w2, g2, b2, m2, v2,
                                               out_feat);
}